// Round 7
// baseline (171.005 us; speedup 1.0000x reference)
//
#include <hip/hip_runtime.h>
#include <math.h>

constexpr int B = 8, C = 32, K = 5, HW = 65536;
constexpr int K1B  = 64;             // k1 blocks per batch (512 total)
constexpr int K1PX = HW / K1B;       // 1024 px per k1 block
constexpr int NIT  = K1PX / 128;     // 8 staging iterations (128 px each)
constexpr int K3PX = 256;            // px per k3 block
constexpr int K3BLK = HW / K3PX;     // 256 k3 blocks per batch (2048 total)
constexpr int NPART = K3BLK * 4;     // sum partials per (b,k) = 1024
constexpr float NEG_HALF_C_LOG2PI_F = -29.406033062549518f;

typedef __attribute__((ext_vector_type(8))) short bf16x8;
typedef __attribute__((ext_vector_type(4))) float f32x4;

__device__ inline unsigned short f2bf(float f) {  // RNE fp32 -> bf16
  unsigned int u = __float_as_uint(f);
  return (unsigned short)((u + 0x7fffu + ((u >> 16) & 1u)) >> 16);
}

// ---------------------------------------------------------------------------
// Kernel 1: per-batch Gram of X = [z(32); g(5); ones] via bf16 MFMA (RNE,
// no lo-split: zero-mean rounding over 65536-px sums -> gram rel err ~8e-6,
// parameter-level only). 6 lower-triangle 16x16 tiles, 6 MFMA/iter.
// Per-block partial (6*256 fp32) to global.
// ---------------------------------------------------------------------------
__global__ __launch_bounds__(256) void k1_gram(const float* __restrict__ z,
                                               const float* __restrict__ g,
                                               float* __restrict__ part) {
  __shared__ __align__(16) unsigned short xs[96 * 136];  // staging uses rows 0-47; tail reuses as fp32 fb
  unsigned int* xsu = (unsigned int*)xs;
  const int tid  = threadIdx.x;
  const int lane = tid & 63;
  const int w    = tid >> 6;
  const int b    = blockIdx.x / K1B;
  const int blk  = blockIdx.x % K1B;
  const int px0  = blk * K1PX;

  // constant rows 37 (=ones), 38-47 (=0). cols 0..127 (64 dwords).
  for (int idx = tid; idx < 11 * 64; idx += 256) {
    int row = 37 + (idx >> 6);
    xsu[row * 68 + (idx & 63)] = (row == 37) ? 0x3f803f80u : 0u;
  }

  f32x4 a00 = {0.f,0.f,0.f,0.f}, a10 = {0.f,0.f,0.f,0.f}, a11 = {0.f,0.f,0.f,0.f};
  f32x4 a20 = {0.f,0.f,0.f,0.f}, a21 = {0.f,0.f,0.f,0.f}, a22 = {0.f,0.f,0.f,0.f};

  float2 pre[10];
#pragma unroll
  for (int j = 0; j < 10; ++j) {
    int r = w + 4 * j;
    if (r < 37) {
      const float* src = (r < 32) ? (z + (size_t)(b * C + r) * HW)
                                  : (g + (size_t)(b * K + (r - 32)) * HW);
      pre[j] = ((const float2*)(src + px0))[lane];
    }
  }

  const int lm = lane & 15, q = lane >> 4;
  const int co = w * 32 + q * 8;

  for (int it = 0; it < NIT; ++it) {
    __syncthreads();
#pragma unroll
    for (int j = 0; j < 10; ++j) {
      int r = w + 4 * j;
      if (r < 37)
        xsu[r * 68 + lane] = (unsigned int)f2bf(pre[j].x) | ((unsigned int)f2bf(pre[j].y) << 16);
    }
    __syncthreads();
    if (it + 1 < NIT) {
#pragma unroll
      for (int j = 0; j < 10; ++j) {
        int r = w + 4 * j;
        if (r < 37) {
          const float* src = (r < 32) ? (z + (size_t)(b * C + r) * HW)
                                      : (g + (size_t)(b * K + (r - 32)) * HW);
          pre[j] = ((const float2*)(src + px0 + (it + 1) * 128))[lane];
        }
      }
    }
    bf16x8 f0 = *(const bf16x8*)&xs[(0  + lm) * 136 + co];
    bf16x8 f1 = *(const bf16x8*)&xs[(16 + lm) * 136 + co];
    bf16x8 f2 = *(const bf16x8*)&xs[(32 + lm) * 136 + co];
#define MF(d, x, y) d = __builtin_amdgcn_mfma_f32_16x16x32_bf16(x, y, d, 0, 0, 0)
    MF(a00, f0, f0); MF(a10, f1, f0); MF(a11, f1, f1);
    MF(a20, f2, f0); MF(a21, f2, f1); MF(a22, f2, f2);
#undef MF
  }

  __syncthreads();
  float* fb = (float*)xs;   // 4 waves * 6 tiles * 4 regs * 64 lanes = 24 KB
#pragma unroll
  for (int rr = 0; rr < 4; ++rr) {
    fb[((w * 6 + 0) * 4 + rr) * 64 + lane] = a00[rr];
    fb[((w * 6 + 1) * 4 + rr) * 64 + lane] = a10[rr];
    fb[((w * 6 + 2) * 4 + rr) * 64 + lane] = a11[rr];
    fb[((w * 6 + 3) * 4 + rr) * 64 + lane] = a20[rr];
    fb[((w * 6 + 4) * 4 + rr) * 64 + lane] = a21[rr];
    fb[((w * 6 + 5) * 4 + rr) * 64 + lane] = a22[rr];
  }
  __syncthreads();
  float* po = part + (size_t)blockIdx.x * 1536;
#pragma unroll
  for (int t = 0; t < 6; ++t) {
    int sl = (tid >> 6), ln = (tid & 63);
    float v = fb[((0 * 6 + t) * 4 + sl) * 64 + ln] + fb[((1 * 6 + t) * 4 + sl) * 64 + ln]
            + fb[((2 * 6 + t) * 4 + sl) * 64 + ln] + fb[((3 * 6 + t) * 4 + sl) * 64 + ln];
    po[t * 256 + tid] = v;
  }
}

// ---------------------------------------------------------------------------
// Kernel 2 (absorbs old k1b): per-(b,k) setup, one 64-thread block each.
// Phase A: reduce this batch's 64 partials (float4 loads, 4-deep unroll)
// into LDS gram[40][40] (decode MFMA C-layout, symmetrize). Phase B:
// wave-parallel fp32 register Cholesky + triangular inverse (proven R4/R6;
// launch_bounds(64) => no VGPR cap, no spills). Zeroes the k4 counter.
// ---------------------------------------------------------------------------
__global__ __launch_bounds__(64) void k2_setup(const float* __restrict__ part,
                                               unsigned short* __restrict__ ABout,
                                               float* __restrict__ vout,
                                               float* __restrict__ cterm,
                                               unsigned int* __restrict__ counter) {
  const int b = blockIdx.x / K, k = blockIdx.x % K;
  const int lane = threadIdx.x;        // 0..63; lanes 32-63 mirror 0-31
  const int j32 = lane & 31;
  __shared__ float gram[1600];
  __shared__ float Amat[32][33];
  __shared__ float mus[32];
  if (blockIdx.x == 0 && lane == 0) *counter = 0u;

  // ---- Phase A: per-block reduction of part1 -> LDS gram ----
  {
    f32x4 accs[6];
#pragma unroll
    for (int j = 0; j < 6; ++j) accs[j] = (f32x4){0.f, 0.f, 0.f, 0.f};
    const float* pb = part + (size_t)(b * K1B) * 1536 + 4 * lane;
#pragma unroll 4
    for (int blk = 0; blk < K1B; ++blk) {
      const float* pp = pb + (size_t)blk * 1536;
#pragma unroll
      for (int j = 0; j < 6; ++j) {
        const f32x4 v = *(const f32x4*)(pp + j * 256);
#pragma unroll
        for (int c = 0; c < 4; ++c) accs[j][c] += v[c];
      }
    }
    const int TI[6] = {0, 1, 1, 2, 2, 2};
    const int TJ[6] = {0, 0, 1, 0, 1, 2};
#pragma unroll
    for (int j = 0; j < 6; ++j) {
#pragma unroll
      for (int c = 0; c < 4; ++c) {
        const int idx = 4 * lane + c;           // tile element (reg*64+lane)
        const int rr = idx >> 6, ln = idx & 63;
        const int m = (ln >> 4) * 4 + rr, n = ln & 15;
        const int gr = TI[j] * 16 + m, gc = TJ[j] * 16 + n;
        if (gr < 40 && gc < 40) {
          gram[gr * 40 + gc] = accs[j][c];
          gram[gc * 40 + gr] = accs[j][c];      // same bits (symmetric products)
        }
      }
    }
  }
  __syncthreads();
  const float* G = gram;

  // ---- Phase B: register Cholesky / inverse (identical to R6 k2) ----
  const float sg = G[37 * 40 + 32 + k];
  float muj = G[(32 + k) * 40 + j32] / (sg + 1e-6f);
  const float szj = G[37 * 40 + j32];
  float nrm = muj * muj;
#pragma unroll
  for (int d = 1; d < 32; d <<= 1) nrm += __shfl_xor(nrm, d, 64);
  muj *= 1.f / (1e-6f + sqrtf(nrm));
  if (lane < 32) mus[lane] = muj;

  float col[32];
#pragma unroll
  for (int i = 0; i < 32; ++i) {
    const float mu_i = __shfl(muj, i, 64);
    const float sz_i = __shfl(szj, i, 64);
    float cv = G[i * 40 + j32] - mu_i * szj - muj * sz_i + 65536.f * mu_i * muj;
    if (i == lane) cv += fmaxf(cv, 1e-6f);
    col[i] = cv;
  }
  float fs = 0.f;
#pragma unroll
  for (int i = 0; i < 32; ++i) fs = fmaf(col[i], col[i], fs);
#pragma unroll
  for (int d = 1; d < 32; d <<= 1) fs += __shfl_xor(fs, d, 64);
  const float fsc = 1.f / (1e-6f + sqrtf(fs));
#pragma unroll
  for (int i = 0; i < 32; ++i) col[i] *= fsc;

  float sown = 0.f, dcap = 1.f;
#pragma unroll
  for (int j = 0; j < 32; ++j) {
    float dd = __shfl(col[j], j, 64);
    dd = fmaxf(dd, 1e-30f);
    const float s = 1.f / sqrtf(dd);
    if (lane == j) { sown = s; dcap = dd; }
    const float f = (lane > j) ? col[j] * s : 0.f;
#pragma unroll
    for (int i = j + 1; i < 32; ++i) {
      const float cji = __shfl(col[i], j, 64) * s;
      col[i] = fmaf(-cji, f, col[i]);
    }
  }

  float Lc[32];
#pragma unroll
  for (int i = 0; i < 32; ++i) Lc[i] = col[i] * sown;

  float x[32];
#pragma unroll
  for (int i = 0; i < 32; ++i) {
    float t0 = (lane == i) ? 1.f : 0.f, t1 = 0.f, t2 = 0.f, t3 = 0.f;
#pragma unroll
    for (int qq = 0; qq < i; ++qq) {
      const float lq = __shfl(Lc[i], qq, 64);
      const float p = lq * x[qq];
      if ((qq & 3) == 0) t0 -= p;
      else if ((qq & 3) == 1) t1 -= p;
      else if ((qq & 3) == 2) t2 -= p;
      else t3 -= p;
    }
    const float Lii = __shfl(Lc[i], i, 64);
    x[i] = ((t0 + t1) + (t2 + t3)) / Lii;
  }

  if (lane < 32) {
#pragma unroll
    for (int i = 0; i < 32; ++i) Amat[i][lane] = x[i];
  }
  __syncthreads();

  if (lane < 32) {
    float t = 0.f;
    for (int d2 = 0; d2 <= lane; ++d2) t = fmaf(Amat[lane][d2], mus[d2], t);
    vout[(b * K + k) * 32 + lane] = t;
  }

  float lg = 0.5f * logf(dcap);
#pragma unroll
  for (int d = 1; d < 32; d <<= 1) lg += __shfl_xor(lg, d, 64);
  if (lane == 0)
    cterm[b * K + k] = NEG_HALF_C_LOG2PI_F - lg + sg / 65536.f;

  unsigned short* Ao = ABout + (size_t)(b * K + k) * 2048;
#pragma unroll
  for (int e = lane; e < 1024; e += 64) {
    const int m = e >> 5, d2 = e & 31;
    const float a = Amat[m][d2];
    const unsigned int u = __float_as_uint(a);
    const float hf = __uint_as_float(u & 0xffff0000u);
    Ao[e] = (unsigned short)(u >> 16);
    Ao[1024 + e] = (unsigned short)(__float_as_uint(a - hf) >> 16);
  }
}

// ---------------------------------------------------------------------------
// Kernel 3: maha via MFMA. Y = (A_h + A_l) * Z_bf16 - v; maha = sum_c Y^2.
// Fixed-offset accumulation: since maha >= 0, S = sum exp(-0.5*maha) is
// computed directly (terms <= 1; underflowing tail terms are below fp32-eps
// of S, same as in the reference's lse). No online max/rescale needed.
// ---------------------------------------------------------------------------
__global__ __launch_bounds__(256) void k3_maha(const float* __restrict__ z,
                                               const unsigned short* __restrict__ AB,
                                               const float* __restrict__ vglob,
                                               float* __restrict__ partials) {
  __shared__ __align__(16) unsigned short zt[K3PX * 40];   // 20 KB
  const int tid  = threadIdx.x;
  const int lane = tid & 63;
  const int w    = tid >> 6;
  const int b    = blockIdx.x / K3BLK;
  const int chb  = blockIdx.x % K3BLK;
  const int px0  = chb * K3PX;

  // stage: wave w handles c-group w (8 c), lane covers px 4*lane..+3
  {
    const float* zb = z + (size_t)b * C * HW + px0 + 4 * lane;
    float4 rv[8];
#pragma unroll
    for (int i = 0; i < 8; ++i)
      rv[i] = *(const float4*)(zb + (size_t)(w * 8 + i) * HW);
#pragma unroll
    for (int p = 0; p < 4; ++p) {
      unsigned int hh[4];
#pragma unroll
      for (int i = 0; i < 8; i += 2) {
        const float a0 = (&rv[i].x)[p], a1 = (&rv[i + 1].x)[p];
        hh[i >> 1] = (unsigned int)f2bf(a0) | ((unsigned int)f2bf(a1) << 16);
      }
      *(uint4*)&zt[(4 * lane + p) * 40 + w * 8] = make_uint4(hh[0], hh[1], hh[2], hh[3]);
    }
  }
  __syncthreads();

  // preload A fragments (hi/lo) and C-init (-v) for all k, mt
  const int lm = lane & 15, q = lane >> 4;
  bf16x8 Ah[K][2], Al[K][2];
  f32x4 Ci[K][2];
#pragma unroll
  for (int k = 0; k < K; ++k) {
    const unsigned short* Abase = AB + (size_t)(b * K + k) * 2048;
    const float* vb = vglob + (size_t)(b * K + k) * 32;
#pragma unroll
    for (int mt = 0; mt < 2; ++mt) {
      const int m = mt * 16 + lm;
      Ah[k][mt] = *(const bf16x8*)(Abase + m * 32 + q * 8);
      Al[k][mt] = *(const bf16x8*)(Abase + 1024 + m * 32 + q * 8);
#pragma unroll
      for (int r = 0; r < 4; ++r)
        Ci[k][mt][r] = -vb[mt * 16 + q * 4 + r];
    }
  }

  float sacc[K];
#pragma unroll
  for (int k = 0; k < K; ++k) sacc[k] = 0.f;

#pragma unroll
  for (int nt = 0; nt < 4; ++nt) {
    const int px = w * 64 + nt * 16 + lm;
    bf16x8 zh = *(const bf16x8*)&zt[px * 40 + q * 8];
#pragma unroll
    for (int k = 0; k < K; ++k) {
      float acc = 0.f;
#pragma unroll
      for (int mt = 0; mt < 2; ++mt) {
        f32x4 y = Ci[k][mt];
        y = __builtin_amdgcn_mfma_f32_16x16x32_bf16(Ah[k][mt], zh, y, 0, 0, 0);
        y = __builtin_amdgcn_mfma_f32_16x16x32_bf16(Al[k][mt], zh, y, 0, 0, 0);
#pragma unroll
        for (int r = 0; r < 4; ++r) acc = fmaf(y[r], y[r], acc);
      }
      acc += __shfl_xor(acc, 16, 64);   // full 32-row maha, dup'd across quads
      acc += __shfl_xor(acc, 32, 64);
      sacc[k] += __expf(-0.5f * acc);
    }
  }
  // sum the 16 px within each quad (quads hold identical copies)
#pragma unroll
  for (int k = 0; k < K; ++k) {
    float s = sacc[k];
#pragma unroll
    for (int d = 1; d < 16; d <<= 1) s += __shfl_xor(s, d, 64);
    if (lane == 0)
      partials[((size_t)(b * K + k) * K3BLK + chb) * 4 + w] = s;
  }
}

// ---------------------------------------------------------------------------
// Kernel 4: per-(b,k) plain sum of NPART partials -> log + cterm; last block
// (device-scope counter) merges all 40 -> energy.
// ---------------------------------------------------------------------------
__global__ __launch_bounds__(64) void k4_final(const float* __restrict__ partials,
                                               const float* __restrict__ cterm,
                                               float* __restrict__ lsebuf,
                                               unsigned int* __restrict__ counter,
                                               float* __restrict__ out) {
  const int bk = blockIdx.x;     // 0..39
  const int lane = threadIdx.x;  // 64
  const float* p = partials + (size_t)bk * NPART;
  float S = 0.f;
#pragma unroll 4
  for (int i = lane; i < NPART; i += 64) S += p[i];
#pragma unroll
  for (int d = 1; d < 64; d <<= 1) S += __shfl_xor(S, d, 64);
  __shared__ int last;
  if (lane == 0) {
    atomicExch(&lsebuf[bk], logf(fmaxf(S, 1e-37f)) + cterm[bk]);
    __threadfence();
    last = (atomicAdd(counter, 1u) == 39u) ? 1 : 0;
  }
  __syncthreads();
  if (last) {
    const float v = (lane < 40) ? atomicAdd(&lsebuf[lane], 0.f) : 0.f;
    double dv = (double)v;
#pragma unroll
    for (int d = 1; d < 64; d <<= 1) dv += __shfl_xor(dv, d, 64);
    if (lane == 0) out[0] = (float)(-dv / (40.0 * 65536.0));
  }
}

extern "C" void kernel_launch(void* const* d_in, const int* in_sizes, int n_in,
                              void* d_out, int out_size, void* d_ws, size_t ws_size,
                              hipStream_t stream) {
  const float* z = (const float*)d_in[0];
  const float* g = (const float*)d_in[1];
  float* out = (float*)d_out;

  // workspace layout (~3.4 MB)
  float*  part3 = (float*)d_ws;                               // 40*1024 floats
  float*  part1 = part3 + 40 * NPART;                         // 512*1536 floats
  unsigned short* AB = (unsigned short*)(part1 + (size_t)(B * K1B) * 1536); // 40*2048
  float*  vv     = (float*)(AB + 40 * 2048);                  // 8*5*32
  float*  ct     = vv + B * K * 32;                           // 40
  float*  lsebuf = ct + B * K;                                // 40
  unsigned int* counter = (unsigned int*)(lsebuf + 40);       // 1

  k1_gram<<<B * K1B, 256, 0, stream>>>(z, g, part1);
  k2_setup<<<B * K, 64, 0, stream>>>(part1, AB, vv, ct, counter);
  k3_maha<<<B * K3BLK, 256, 0, stream>>>(z, AB, vv, part3);
  k4_final<<<B * K, 64, 0, stream>>>(part3, ct, lsebuf, counter, out);
}

// Round 8
// 161.845 us; speedup vs baseline: 1.0566x; 1.0566x over previous
//
#include <hip/hip_runtime.h>
#include <math.h>

constexpr int B = 8, C = 32, K = 5, HW = 65536;
constexpr int K1B  = 64;             // k1 blocks per batch (512 total)
constexpr int K1PX = HW / K1B;       // 1024 px per k1 block
constexpr int NIT  = K1PX / 128;     // 8 staging iterations (128 px each)
constexpr int K3PX = 256;            // px per k3 block
constexpr int K3BLK = HW / K3PX;     // 256 k3 blocks per batch (2048 total)
constexpr int NPART = K3BLK * 4;     // sum partials per (b,k) = 1024
constexpr float NEG_HALF_C_LOG2PI_F = -29.406033062549518f;

typedef __attribute__((ext_vector_type(8))) short bf16x8;
typedef __attribute__((ext_vector_type(4))) float f32x4;

__device__ inline unsigned short f2bf(float f) {  // RNE fp32 -> bf16
  unsigned int u = __float_as_uint(f);
  return (unsigned short)((u + 0x7fffu + ((u >> 16) & 1u)) >> 16);
}

// ---------------------------------------------------------------------------
// Kernel 1: per-batch Gram of X = [z(32); g(5); ones] via bf16 MFMA (RNE,
// no lo-split: zero-mean rounding over 65536-px sums -> gram rel err ~8e-6,
// parameter-level only). 6 lower-triangle 16x16 tiles, 6 MFMA/iter.
// Per-block partial (6*256 fp32) to global.
// ---------------------------------------------------------------------------
__global__ __launch_bounds__(256) void k1_gram(const float* __restrict__ z,
                                               const float* __restrict__ g,
                                               float* __restrict__ part) {
  __shared__ __align__(16) unsigned short xs[96 * 136];
  unsigned int* xsu = (unsigned int*)xs;
  const int tid  = threadIdx.x;
  const int lane = tid & 63;
  const int w    = tid >> 6;
  const int b    = blockIdx.x / K1B;
  const int blk  = blockIdx.x % K1B;
  const int px0  = blk * K1PX;

  // constant rows 37 (=ones), 38-47 (=0). cols 0..127 (64 dwords).
  for (int idx = tid; idx < 11 * 64; idx += 256) {
    int row = 37 + (idx >> 6);
    xsu[row * 68 + (idx & 63)] = (row == 37) ? 0x3f803f80u : 0u;
  }

  f32x4 a00 = {0.f,0.f,0.f,0.f}, a10 = {0.f,0.f,0.f,0.f}, a11 = {0.f,0.f,0.f,0.f};
  f32x4 a20 = {0.f,0.f,0.f,0.f}, a21 = {0.f,0.f,0.f,0.f}, a22 = {0.f,0.f,0.f,0.f};

  float2 pre[10];
#pragma unroll
  for (int j = 0; j < 10; ++j) {
    int r = w + 4 * j;
    if (r < 37) {
      const float* src = (r < 32) ? (z + (size_t)(b * C + r) * HW)
                                  : (g + (size_t)(b * K + (r - 32)) * HW);
      pre[j] = ((const float2*)(src + px0))[lane];
    }
  }

  const int lm = lane & 15, q = lane >> 4;
  const int co = w * 32 + q * 8;

  for (int it = 0; it < NIT; ++it) {
    __syncthreads();
#pragma unroll
    for (int j = 0; j < 10; ++j) {
      int r = w + 4 * j;
      if (r < 37)
        xsu[r * 68 + lane] = (unsigned int)f2bf(pre[j].x) | ((unsigned int)f2bf(pre[j].y) << 16);
    }
    __syncthreads();
    if (it + 1 < NIT) {
#pragma unroll
      for (int j = 0; j < 10; ++j) {
        int r = w + 4 * j;
        if (r < 37) {
          const float* src = (r < 32) ? (z + (size_t)(b * C + r) * HW)
                                      : (g + (size_t)(b * K + (r - 32)) * HW);
          pre[j] = ((const float2*)(src + px0 + (it + 1) * 128))[lane];
        }
      }
    }
    bf16x8 f0 = *(const bf16x8*)&xs[(0  + lm) * 136 + co];
    bf16x8 f1 = *(const bf16x8*)&xs[(16 + lm) * 136 + co];
    bf16x8 f2 = *(const bf16x8*)&xs[(32 + lm) * 136 + co];
#define MF(d, x, y) d = __builtin_amdgcn_mfma_f32_16x16x32_bf16(x, y, d, 0, 0, 0)
    MF(a00, f0, f0); MF(a10, f1, f0); MF(a11, f1, f1);
    MF(a20, f2, f0); MF(a21, f2, f1); MF(a22, f2, f2);
#undef MF
  }

  __syncthreads();
  float* fb = (float*)xs;   // 4 waves * 6 tiles * 4 regs * 64 lanes = 24 KB
#pragma unroll
  for (int rr = 0; rr < 4; ++rr) {
    fb[((w * 6 + 0) * 4 + rr) * 64 + lane] = a00[rr];
    fb[((w * 6 + 1) * 4 + rr) * 64 + lane] = a10[rr];
    fb[((w * 6 + 2) * 4 + rr) * 64 + lane] = a11[rr];
    fb[((w * 6 + 3) * 4 + rr) * 64 + lane] = a20[rr];
    fb[((w * 6 + 4) * 4 + rr) * 64 + lane] = a21[rr];
    fb[((w * 6 + 5) * 4 + rr) * 64 + lane] = a22[rr];
  }
  __syncthreads();
  float* po = part + (size_t)blockIdx.x * 1536;
#pragma unroll
  for (int t = 0; t < 6; ++t) {
    int sl = (tid >> 6), ln = (tid & 63);
    float v = fb[((0 * 6 + t) * 4 + sl) * 64 + ln] + fb[((1 * 6 + t) * 4 + sl) * 64 + ln]
            + fb[((2 * 6 + t) * 4 + sl) * 64 + ln] + fb[((3 * 6 + t) * 4 + sl) * 64 + ln];
    po[t * 256 + tid] = v;
  }
}

// ---------------------------------------------------------------------------
// Kernel 1b: sum per-block partials (fp64 accum, 8-way load ILP), decode MFMA
// C-layout, symmetrize. Grid 48 = 8 b x 6 tiles, 192 waves — bulk data needs
// parallel waves (single-wave phase-A fusion in R7 cost 43 us, latency-bound).
// ---------------------------------------------------------------------------
__global__ void k1b_reduce(const float* __restrict__ part, float* __restrict__ gram) {
  const int b = blockIdx.x / 6, t = blockIdx.x % 6;
  const int tid = threadIdx.x;     // 256
  const int rr = tid >> 6, lane = tid & 63;
  const int m = (lane >> 4) * 4 + rr, n = lane & 15;
  const int TI[6] = {0, 1, 1, 2, 2, 2};
  const int TJ[6] = {0, 0, 1, 0, 1, 2};
  double s = 0.0;
#pragma unroll 8
  for (int blk = 0; blk < K1B; ++blk)
    s += (double)part[(size_t)(b * K1B + blk) * 1536 + t * 256 + tid];
  int gr = TI[t] * 16 + m, gc = TJ[t] * 16 + n;
  if (gr < 40 && gc < 40) {
    gram[b * 1600 + gr * 40 + gc] = (float)s;
    gram[b * 1600 + gc * 40 + gr] = (float)s;
  }
}

// ---------------------------------------------------------------------------
// Kernel 2: per-(b,k) setup, wave-parallel fp32 in registers. Reads only the
// 6.4 KB gram. 64-thread blocks, launch_bounds(64): no VGPR cap, no spills
// (proven ~4 us in R4/R6). Zeroes the k4 counter.
// ---------------------------------------------------------------------------
__global__ __launch_bounds__(64) void k2_setup(const float* __restrict__ gram,
                                               unsigned short* __restrict__ ABout,
                                               float* __restrict__ vout,
                                               float* __restrict__ cterm,
                                               unsigned int* __restrict__ counter) {
  const int b = blockIdx.x / K, k = blockIdx.x % K;
  const float* G = gram + b * 1600;
  const int lane = threadIdx.x;        // 0..63; lanes 32-63 mirror 0-31
  const int j32 = lane & 31;
  __shared__ float Amat[32][33];
  __shared__ float mus[32];
  if (blockIdx.x == 0 && lane == 0) *counter = 0u;

  const float sg = G[37 * 40 + 32 + k];
  float muj = G[(32 + k) * 40 + j32] / (sg + 1e-6f);
  const float szj = G[37 * 40 + j32];
  float nrm = muj * muj;
#pragma unroll
  for (int d = 1; d < 32; d <<= 1) nrm += __shfl_xor(nrm, d, 64);
  muj *= 1.f / (1e-6f + sqrtf(nrm));
  if (lane < 32) mus[lane] = muj;

  // full symmetric cov column j=lane, diag-doubled
  float col[32];
#pragma unroll
  for (int i = 0; i < 32; ++i) {
    const float mu_i = __shfl(muj, i, 64);
    const float sz_i = __shfl(szj, i, 64);
    float cv = G[i * 40 + j32] - mu_i * szj - muj * sz_i + 65536.f * mu_i * muj;
    if (i == lane) cv += fmaxf(cv, 1e-6f);
    col[i] = cv;
  }
  // Frobenius normalize
  float fs = 0.f;
#pragma unroll
  for (int i = 0; i < 32; ++i) fs = fmaf(col[i], col[i], fs);
#pragma unroll
  for (int d = 1; d < 32; d <<= 1) fs += __shfl_xor(fs, d, 64);
  const float fsc = 1.f / (1e-6f + sqrtf(fs));
#pragma unroll
  for (int i = 0; i < 32; ++i) col[i] *= fsc;

  // right-looking Cholesky
  float sown = 0.f, dcap = 1.f;
#pragma unroll
  for (int j = 0; j < 32; ++j) {
    float dd = __shfl(col[j], j, 64);
    dd = fmaxf(dd, 1e-30f);
    const float s = 1.f / sqrtf(dd);
    if (lane == j) { sown = s; dcap = dd; }
    const float f = (lane > j) ? col[j] * s : 0.f;
#pragma unroll
    for (int i = j + 1; i < 32; ++i) {
      const float cji = __shfl(col[i], j, 64) * s;
      col[i] = fmaf(-cji, f, col[i]);
    }
  }

  float Lc[32];
#pragma unroll
  for (int i = 0; i < 32; ++i) Lc[i] = col[i] * sown;

  // x = column 'lane' of A = L^{-1}
  float x[32];
#pragma unroll
  for (int i = 0; i < 32; ++i) {
    float t0 = (lane == i) ? 1.f : 0.f, t1 = 0.f, t2 = 0.f, t3 = 0.f;
#pragma unroll
    for (int qq = 0; qq < i; ++qq) {
      const float lq = __shfl(Lc[i], qq, 64);
      const float p = lq * x[qq];
      if ((qq & 3) == 0) t0 -= p;
      else if ((qq & 3) == 1) t1 -= p;
      else if ((qq & 3) == 2) t2 -= p;
      else t3 -= p;
    }
    const float Lii = __shfl(Lc[i], i, 64);
    x[i] = ((t0 + t1) + (t2 + t3)) / Lii;
  }

  if (lane < 32) {
#pragma unroll
    for (int i = 0; i < 32; ++i) Amat[i][lane] = x[i];
  }
  __syncthreads();

  // v = A * mu (row 'lane'); A strictly lower+diag
  if (lane < 32) {
    float t = 0.f;
    for (int d2 = 0; d2 <= lane; ++d2) t = fmaf(Amat[lane][d2], mus[d2], t);
    vout[(b * K + k) * 32 + lane] = t;
  }

  // cterm = -0.5*c*log2pi - 0.5*logdet + phi
  float lg = 0.5f * logf(dcap);
#pragma unroll
  for (int d = 1; d < 32; d <<= 1) lg += __shfl_xor(lg, d, 64);
  if (lane == 0)
    cterm[b * K + k] = NEG_HALF_C_LOG2PI_F - lg + sg / 65536.f;

  // bf16 hi/lo split of A (row-major 32x32 each)
  unsigned short* Ao = ABout + (size_t)(b * K + k) * 2048;
#pragma unroll
  for (int e = lane; e < 1024; e += 64) {
    const int m = e >> 5, d2 = e & 31;
    const float a = Amat[m][d2];
    const unsigned int u = __float_as_uint(a);
    const float hf = __uint_as_float(u & 0xffff0000u);
    Ao[e] = (unsigned short)(u >> 16);
    Ao[1024 + e] = (unsigned short)(__float_as_uint(a - hf) >> 16);
  }
}

// ---------------------------------------------------------------------------
// Kernel 3: maha via MFMA. Y = (A_h + A_l) * Z_bf16 - v; maha = sum_c Y^2.
// Fixed-offset accumulation: since maha >= 0, S = sum exp(-0.5*maha) is
// computed directly (terms <= 1; underflowing tail terms are below fp32-eps
// of S, same as in the reference's lse).
// ---------------------------------------------------------------------------
__global__ __launch_bounds__(256) void k3_maha(const float* __restrict__ z,
                                               const unsigned short* __restrict__ AB,
                                               const float* __restrict__ vglob,
                                               float* __restrict__ partials) {
  __shared__ __align__(16) unsigned short zt[K3PX * 40];   // 20 KB
  const int tid  = threadIdx.x;
  const int lane = tid & 63;
  const int w    = tid >> 6;
  const int b    = blockIdx.x / K3BLK;
  const int chb  = blockIdx.x % K3BLK;
  const int px0  = chb * K3PX;

  // stage: wave w handles c-group w (8 c), lane covers px 4*lane..+3
  {
    const float* zb = z + (size_t)b * C * HW + px0 + 4 * lane;
    float4 rv[8];
#pragma unroll
    for (int i = 0; i < 8; ++i)
      rv[i] = *(const float4*)(zb + (size_t)(w * 8 + i) * HW);
#pragma unroll
    for (int p = 0; p < 4; ++p) {
      unsigned int hh[4];
#pragma unroll
      for (int i = 0; i < 8; i += 2) {
        const float a0 = (&rv[i].x)[p], a1 = (&rv[i + 1].x)[p];
        hh[i >> 1] = (unsigned int)f2bf(a0) | ((unsigned int)f2bf(a1) << 16);
      }
      *(uint4*)&zt[(4 * lane + p) * 40 + w * 8] = make_uint4(hh[0], hh[1], hh[2], hh[3]);
    }
  }
  __syncthreads();

  // preload A fragments (hi/lo) and C-init (-v) for all k, mt
  const int lm = lane & 15, q = lane >> 4;
  bf16x8 Ah[K][2], Al[K][2];
  f32x4 Ci[K][2];
#pragma unroll
  for (int k = 0; k < K; ++k) {
    const unsigned short* Abase = AB + (size_t)(b * K + k) * 2048;
    const float* vb = vglob + (size_t)(b * K + k) * 32;
#pragma unroll
    for (int mt = 0; mt < 2; ++mt) {
      const int m = mt * 16 + lm;
      Ah[k][mt] = *(const bf16x8*)(Abase + m * 32 + q * 8);
      Al[k][mt] = *(const bf16x8*)(Abase + 1024 + m * 32 + q * 8);
#pragma unroll
      for (int r = 0; r < 4; ++r)
        Ci[k][mt][r] = -vb[mt * 16 + q * 4 + r];
    }
  }

  float sacc[K];
#pragma unroll
  for (int k = 0; k < K; ++k) sacc[k] = 0.f;

#pragma unroll
  for (int nt = 0; nt < 4; ++nt) {
    const int px = w * 64 + nt * 16 + lm;
    bf16x8 zh = *(const bf16x8*)&zt[px * 40 + q * 8];
#pragma unroll
    for (int k = 0; k < K; ++k) {
      float acc = 0.f;
#pragma unroll
      for (int mt = 0; mt < 2; ++mt) {
        f32x4 y = Ci[k][mt];
        y = __builtin_amdgcn_mfma_f32_16x16x32_bf16(Ah[k][mt], zh, y, 0, 0, 0);
        y = __builtin_amdgcn_mfma_f32_16x16x32_bf16(Al[k][mt], zh, y, 0, 0, 0);
#pragma unroll
        for (int r = 0; r < 4; ++r) acc = fmaf(y[r], y[r], acc);
      }
      acc += __shfl_xor(acc, 16, 64);   // full 32-row maha, dup'd across quads
      acc += __shfl_xor(acc, 32, 64);
      sacc[k] += __expf(-0.5f * acc);
    }
  }
  // sum the 16 px within each quad (quads hold identical copies)
#pragma unroll
  for (int k = 0; k < K; ++k) {
    float s = sacc[k];
#pragma unroll
    for (int d = 1; d < 16; d <<= 1) s += __shfl_xor(s, d, 64);
    if (lane == 0)
      partials[((size_t)(b * K + k) * K3BLK + chb) * 4 + w] = s;
  }
}

// ---------------------------------------------------------------------------
// Kernel 4: per-(b,k) plain sum of NPART partials -> log + cterm; last block
// (device-scope counter) merges all 40 -> energy.
// ---------------------------------------------------------------------------
__global__ __launch_bounds__(64) void k4_final(const float* __restrict__ partials,
                                               const float* __restrict__ cterm,
                                               float* __restrict__ lsebuf,
                                               unsigned int* __restrict__ counter,
                                               float* __restrict__ out) {
  const int bk = blockIdx.x;     // 0..39
  const int lane = threadIdx.x;  // 64
  const float* p = partials + (size_t)bk * NPART;
  float S = 0.f;
#pragma unroll 4
  for (int i = lane; i < NPART; i += 64) S += p[i];
#pragma unroll
  for (int d = 1; d < 64; d <<= 1) S += __shfl_xor(S, d, 64);
  __shared__ int last;
  if (lane == 0) {
    atomicExch(&lsebuf[bk], logf(fmaxf(S, 1e-37f)) + cterm[bk]);
    __threadfence();
    last = (atomicAdd(counter, 1u) == 39u) ? 1 : 0;
  }
  __syncthreads();
  if (last) {
    const float v = (lane < 40) ? atomicAdd(&lsebuf[lane], 0.f) : 0.f;
    double dv = (double)v;
#pragma unroll
    for (int d = 1; d < 64; d <<= 1) dv += __shfl_xor(dv, d, 64);
    if (lane == 0) out[0] = (float)(-dv / (40.0 * 65536.0));
  }
}

extern "C" void kernel_launch(void* const* d_in, const int* in_sizes, int n_in,
                              void* d_out, int out_size, void* d_ws, size_t ws_size,
                              hipStream_t stream) {
  const float* z = (const float*)d_in[0];
  const float* g = (const float*)d_in[1];
  float* out = (float*)d_out;

  // workspace layout (~3.4 MB)
  float*  part3 = (float*)d_ws;                               // 40*1024 floats
  float*  part1 = part3 + 40 * NPART;                         // 512*1536 floats
  unsigned short* AB = (unsigned short*)(part1 + (size_t)(B * K1B) * 1536); // 40*2048
  float*  gram   = (float*)(AB + 40 * 2048);                  // 8*1600
  float*  vv     = gram + B * 1600;                           // 8*5*32
  float*  ct     = vv + B * K * 32;                           // 40
  float*  lsebuf = ct + B * K;                                // 40
  unsigned int* counter = (unsigned int*)(lsebuf + 40);       // 1

  k1_gram<<<B * K1B, 256, 0, stream>>>(z, g, part1);
  k1b_reduce<<<B * 6, 256, 0, stream>>>(part1, gram);
  k2_setup<<<B * K, 64, 0, stream>>>(gram, AB, vv, ct, counter);
  k3_maha<<<B * K3BLK, 256, 0, stream>>>(z, AB, vv, part3);
  k4_final<<<B * K, 64, 0, stream>>>(part3, ct, lsebuf, counter, out);
}